// Round 9
// baseline (404.581 us; speedup 1.0000x reference)
//
#include <hip/hip_runtime.h>
#include <hip/hip_bf16.h>
#include <math.h>

// audio (16,5,256) -> 4 branches x 3 mamba layers -> gates scale x1..x4.
// R9 model (R5-R8 evidence): all prior chain variants were LDS-pipe-bound in
// the GEMV inner loops (every FMA operand a ds_read). New pattern: lane=token,
// activations in VGPRs, weights via wave-UNIFORM row-major loads (scalar
// /broadcast path, no repack). Inner loops are pure v_fma -> near-peak VALU.

#define NTOK 80
#define DM   256
#define DI   512

typedef float f32x4 __attribute__((ext_vector_type(4)));

__device__ __forceinline__ float silu_f(float v) {
    return v / (1.f + expf(-v));
}
__device__ __forceinline__ float dot4(float4 a, float4 b) {
    return a.x*b.x + a.y*b.y + a.z*b.z + a.w*b.w;
}

// ---- workspace layout (float indices) ----
#define OFF_SG    0        // 81920   gates
#define OFF_A     81920    // 81920   post-layer activations [4][80][256]
#define OFF_ALN   163840   // 81920   LN output (residual base)
#define OFF_XC    245760   // 163840  conv+silu out [4][80][512]
#define OFF_Z     409600   // 163840  z [4][80][512]
#define OFF_Y     573440   // 163840  scan out [4][80][512]
#define OFF_WXT   737280   // 294912  [12][128 k4][48 c] f4

// ---------------- Wx repack only: [48][512] -> [128 k4][48] f4 ----------------
__global__ __launch_bounds__(256) void k_trx(const float* __restrict__ Wx,
                                             float* __restrict__ ws) {
    __shared__ float4 T[3120];
    int b = blockIdx.x, tid = threadIdx.x;
    int il = b >> 1, h = b & 1;
    const float4* src = (const float4*)Wx + (size_t)il * 6144;
    float4* dst = (float4*)(ws + OFF_WXT) + (size_t)il * 6144;
    for (int idx = tid; idx < 3072; idx += 256) {
        int jj = idx >> 6, k4l = idx & 63;
        T[jj * 65 + k4l] = src[(size_t)jj * 128 + 64 * h + k4l];
    }
    __syncthreads();
    for (int idx = tid; idx < 3072; idx += 256) {
        int k4l = idx / 48, jj = idx % 48;
        dst[(size_t)(64 * h + k4l) * 48 + jj] = T[jj * 65 + k4l];
    }
}

// ---------------- K_in: LN + in_proj + conv + SiLU ----------------
// grid 256 = i(4) x cg(64, 16 cols); 256 thr = 4 waves (th = w&1, kh = w>>1)
__global__ __launch_bounds__(256) void K_in(
    const float* __restrict__ src, int srcStride,
    const float* __restrict__ ln_g, const float* __restrict__ ln_b,
    const float* __restrict__ Win,
    const float* __restrict__ Wc,   const float* __restrict__ bc,
    int l, float* __restrict__ ws)
{
    int blk = blockIdx.x;
    int i = blk >> 6, cg = blk & 63;
    int il = i * 3 + l;
    int tid = threadIdx.x, lane = tid & 63, w = tid >> 6;
    int th = w & 1, kh = w >> 1;
    int n = th * 64 + lane;
    bool act = n < NTOK;
    int c0 = cg * 16;

    __shared__ float red_s[2][NTOK][2];
    __shared__ float comb[2][16][NTOK];
    __shared__ float xzc[16][NTOK];

    // ---- load + LN (k-half in registers, per-lane stats + LDS pair-combine) --
    f32x4 av[32];
    float s1 = 0.f, s2 = 0.f;
    if (act) {
        const f32x4* r4 = (const f32x4*)(src + (size_t)i * srcStride
                                         + (size_t)n * DM + kh * 128);
        #pragma unroll
        for (int j = 0; j < 32; ++j) {
            av[j] = r4[j];
            s1 += av[j].x + av[j].y + av[j].z + av[j].w;
            s2 += av[j].x*av[j].x + av[j].y*av[j].y + av[j].z*av[j].z + av[j].w*av[j].w;
        }
        red_s[kh][n][0] = s1;
        red_s[kh][n][1] = s2;
    }
    __syncthreads();
    if (act) {
        float mu  = (red_s[0][n][0] + red_s[1][n][0]) * (1.f / 256.f);
        float var = (red_s[0][n][1] + red_s[1][n][1]) * (1.f / 256.f) - mu * mu;
        float rstd = rsqrtf(var + 1e-5f);
        const f32x4* g4 = (const f32x4*)(ln_g + (size_t)il * DM + kh * 128);
        const f32x4* b4 = (const f32x4*)(ln_b + (size_t)il * DM + kh * 128);
        #pragma unroll
        for (int j = 0; j < 32; ++j)
            av[j] = (av[j] - mu) * rstd * g4[j] + b4[j];
        if (cg == 0) {
            f32x4* alnw = (f32x4*)(ws + OFF_ALN + ((size_t)i * NTOK + n) * DM + kh * 128);
            #pragma unroll
            for (int j = 0; j < 32; ++j) alnw[j] = av[j];
        }
    }

    // ---- GEMV: 16 cols, uniform weight loads, acts in VGPRs ----
    float acc[16];
    const float* wb = Win + ((size_t)il * 1024 + c0) * DM + kh * 128;
    #pragma unroll
    for (int cc = 0; cc < 16; ++cc) {
        const f32x4* w4 = (const f32x4*)(wb + cc * DM);
        float a0 = 0.f;
        #pragma unroll
        for (int j = 0; j < 32; ++j) {
            f32x4 wv = w4[j];
            a0 += wv.x*av[j].x + wv.y*av[j].y + wv.z*av[j].z + wv.w*av[j].w;
        }
        acc[cc] = a0;
    }
    if (act) {
        #pragma unroll
        for (int cc = 0; cc < 16; ++cc) comb[kh][cc][n] = acc[cc];
    }
    __syncthreads();

    if (cg >= 32) {
        // z columns: combine k-halves and store
        if (kh == 0 && act) {
            int zc0 = c0 - 512;
            #pragma unroll
            for (int cc = 0; cc < 16; ++cc)
                ws[OFF_Z + ((size_t)i * NTOK + n) * DI + zc0 + cc] =
                    comb[0][cc][n] + comb[1][cc][n];
        }
    } else {
        // xc columns: combine, then causal conv from LDS + SiLU
        if (kh == 0 && act) {
            #pragma unroll
            for (int cc = 0; cc < 16; ++cc)
                xzc[cc][n] = comb[0][cc][n] + comb[1][cc][n];
        }
        __syncthreads();
        if (kh == 0 && act) {
            int t = n % 5;
            #pragma unroll
            for (int cc = 0; cc < 16; ++cc) {
                int ch = c0 + cc;
                const float* wc = Wc + ((size_t)il * DI + ch) * 4;
                float x = bc[(size_t)il * DI + ch] + wc[3] * xzc[cc][n];
                if (t >= 1) x += wc[2] * xzc[cc][n - 1];
                if (t >= 2) x += wc[1] * xzc[cc][n - 2];
                if (t >= 3) x += wc[0] * xzc[cc][n - 3];
                ws[OFF_XC + ((size_t)i * NTOK + n) * DI + ch] = silu_f(x);
            }
        }
    }
}

// ---------------- K_scan: x_proj + dt + scan + D + z-gate ----------------
// grid 64: i = blk&3, b = blk>>2; 512 threads
__global__ __launch_bounds__(512) void K_scan(
    const float* __restrict__ Wdt, const float* __restrict__ bdt,
    const float* __restrict__ Alog, const float* __restrict__ Dp,
    int l, float* __restrict__ ws)
{
    int blk = blockIdx.x;
    int i = blk & 3, b = blk >> 2;
    int il = i * 3 + l;
    int tid = threadIdx.x;

    __shared__ __align__(16) float xc_l[5 * DI];
    __shared__ __align__(16) float dbl_l[240];
    __shared__ __align__(16) float xp_l[480];

    const float* xc_ws = ws + OFF_XC + ((size_t)i * NTOK + b * 5) * DI;
    for (int v = tid; v < 640; v += 512)
        ((float4*)xc_l)[v] = ((const float4*)xc_ws)[v];
    __syncthreads();

    if (tid < 480) {
        int c = tid % 48, r = (tid / 48) % 5, kh = tid / 240;
        const float4* wp = (const float4*)(ws + OFF_WXT) + (size_t)il * 6144 + c;
        const float4* x4 = (const float4*)xc_l + r * 128 + kh * 64;
        float acc = 0.f;
        #pragma unroll 8
        for (int kk = 0; kk < 64; ++kk)
            acc += dot4(wp[(size_t)(kh * 64 + kk) * 48], x4[kk]);
        xp_l[tid] = acc;
    }
    __syncthreads();
    if (tid < 240) dbl_l[tid] = xp_l[tid] + xp_l[240 + tid];
    __syncthreads();

    {
        int d = tid;
        float A[16], h[16];
        const float4* al4 = (const float4*)(Alog + ((size_t)il * DI + d) * 16);
        float4 av0 = al4[0], av1 = al4[1], av2 = al4[2], av3 = al4[3];
        A[0]=-expf(av0.x); A[1]=-expf(av0.y); A[2]=-expf(av0.z); A[3]=-expf(av0.w);
        A[4]=-expf(av1.x); A[5]=-expf(av1.y); A[6]=-expf(av1.z); A[7]=-expf(av1.w);
        A[8]=-expf(av2.x); A[9]=-expf(av2.y); A[10]=-expf(av2.z); A[11]=-expf(av2.w);
        A[12]=-expf(av3.x); A[13]=-expf(av3.y); A[14]=-expf(av3.z); A[15]=-expf(av3.w);
        #pragma unroll
        for (int nn = 0; nn < 16; ++nn) h[nn] = 0.f;
        const float4* wd4 = (const float4*)(Wdt + ((size_t)il * DI + d) * 16);
        float4 w0 = wd4[0], w1 = wd4[1], w2 = wd4[2], w3 = wd4[3];
        float bdtv = bdt[(size_t)il * DI + d];
        float dv   = Dp[(size_t)il * DI + d];
        const float* z_ws = ws + OFF_Z + ((size_t)i * NTOK + b * 5) * DI + d;
        float* y_ws       = ws + OFF_Y + ((size_t)i * NTOK + b * 5) * DI + d;
        #pragma unroll
        for (int t = 0; t < 5; ++t) {
            const float* db = dbl_l + t * 48;
            float acc = bdtv;
            acc += db[0]*w0.x + db[1]*w0.y + db[2]*w0.z + db[3]*w0.w;
            acc += db[4]*w1.x + db[5]*w1.y + db[6]*w1.z + db[7]*w1.w;
            acc += db[8]*w2.x + db[9]*w2.y + db[10]*w2.z + db[11]*w2.w;
            acc += db[12]*w3.x + db[13]*w3.y + db[14]*w3.z + db[15]*w3.w;
            float dtv = fmaxf(acc, 0.f) + log1pf(expf(-fabsf(acc)));
            float xv  = xc_l[t * DI + d];
            float zv  = z_ws[t * DI];
            float dx  = dtv * xv;
            float yacc = 0.f;
            #pragma unroll
            for (int nn = 0; nn < 16; ++nn) {
                h[nn] = expf(dtv * A[nn]) * h[nn] + dx * db[16 + nn];
                yacc += h[nn] * db[32 + nn];
            }
            y_ws[t * DI] = (yacc + xv * dv) * silu_f(zv);
        }
    }
}

// ---------------- K_out: out_proj + residual -> a ----------------
// grid 128 = i(4) x cg(32, 8 cols); 512 thr = 8 waves (th = w&1, kq = w>>1)
__global__ __launch_bounds__(512) void K_out(
    const float* __restrict__ Wout, int l, float* __restrict__ ws)
{
    int blk = blockIdx.x;
    int i = blk >> 5, cg = blk & 31;
    int il = i * 3 + l;
    int tid = threadIdx.x, lane = tid & 63, w = tid >> 6;
    int th = w & 1, kq = w >> 1;
    int n = th * 64 + lane;
    bool act = n < NTOK;
    int c0 = cg * 8;

    __shared__ float part[4][8][NTOK];

    f32x4 yv[32];
    if (act) {
        const f32x4* y4 = (const f32x4*)(ws + OFF_Y + ((size_t)i * NTOK + n) * DI + kq * 128);
        #pragma unroll
        for (int j = 0; j < 32; ++j) yv[j] = y4[j];
    }
    float acc[8];
    const float* wb = Wout + ((size_t)il * DM + c0) * DI + kq * 128;
    #pragma unroll
    for (int cc = 0; cc < 8; ++cc) {
        const f32x4* w4 = (const f32x4*)(wb + cc * DI);
        float a0 = 0.f;
        #pragma unroll
        for (int j = 0; j < 32; ++j) {
            f32x4 wv = w4[j];
            a0 += wv.x*yv[j].x + wv.y*yv[j].y + wv.z*yv[j].z + wv.w*yv[j].w;
        }
        acc[cc] = a0;
    }
    if (act) {
        #pragma unroll
        for (int cc = 0; cc < 8; ++cc) part[kq][cc][n] = acc[cc];
    }
    __syncthreads();
    if (kq == 0 && act) {
        #pragma unroll
        for (int cc = 0; cc < 8; ++cc) {
            size_t idx = ((size_t)i * NTOK + n) * DM + c0 + cc;
            ws[OFF_A + idx] = ws[OFF_ALN + idx]
                + part[0][cc][n] + part[1][cc][n] + part[2][cc][n] + part[3][cc][n];
        }
    }
}

// ---------------- K_gates: s_g = 1+silu(a@gw^T+gb), permuted ----------------
// grid 128 = i(4) x cg(32, 8 cols); 256 thr = 4 waves (th = w&1, kh = w>>1)
__global__ __launch_bounds__(256) void K_gates(
    const float* __restrict__ gw, const float* __restrict__ gb,
    float* __restrict__ ws)
{
    int blk = blockIdx.x;
    int i = blk >> 5, cg = blk & 31;
    int tid = threadIdx.x, lane = tid & 63, w = tid >> 6;
    int th = w & 1, kh = w >> 1;
    int n = th * 64 + lane;
    bool act = n < NTOK;
    int c0 = cg * 8;

    __shared__ float part[2][8][NTOK];

    f32x4 avv[32];
    if (act) {
        const f32x4* a4 = (const f32x4*)(ws + OFF_A + ((size_t)i * NTOK + n) * DM + kh * 128);
        #pragma unroll
        for (int j = 0; j < 32; ++j) avv[j] = a4[j];
    }
    float acc[8];
    const float* wb = gw + ((size_t)i * DM + c0) * DM + kh * 128;
    #pragma unroll
    for (int cc = 0; cc < 8; ++cc) {
        const f32x4* w4 = (const f32x4*)(wb + cc * DM);
        float a0 = 0.f;
        #pragma unroll
        for (int j = 0; j < 32; ++j) {
            f32x4 wv = w4[j];
            a0 += wv.x*avv[j].x + wv.y*avv[j].y + wv.z*avv[j].z + wv.w*avv[j].w;
        }
        acc[cc] = a0;
    }
    if (act) {
        #pragma unroll
        for (int cc = 0; cc < 8; ++cc) part[kh][cc][n] = acc[cc];
    }
    __syncthreads();
    if (kh == 0 && act) {
        int np = (i == 0) ? n : (n % 5) * 16 + n / 5;
        #pragma unroll
        for (int cc = 0; cc < 8; ++cc) {
            float val = gb[(size_t)i * DM + c0 + cc] + part[0][cc][n] + part[1][cc][n];
            ws[OFF_SG + ((size_t)i * NTOK + np) * DM + c0 + cc] = 1.f + silu_f(val);
        }
    }
}

// ---------------- fused elementwise: o = x * s[plane], nontemporal ----------
__global__ __launch_bounds__(256) void k_elem(
    const float* __restrict__ x1, const float* __restrict__ x2,
    const float* __restrict__ x3, const float* __restrict__ x4,
    const float* __restrict__ audio, const float* __restrict__ s_g,
    float* __restrict__ out) {
    int b = blockIdx.x;
    int t = threadIdx.x;

    if (b < 512) {
        const float* s = s_g + 3 * NTOK * DM;
        const f32x4* xv = (const f32x4*)x4;
        f32x4* ov = (f32x4*)out;
        const int total4 = 1003520 / 4;
        for (int v = b * 256 + t; v < total4; v += 512 * 256) {
            f32x4 x = __builtin_nontemporal_load(&xv[v]);
#pragma unroll
            for (int j = 0; j < 4; ++j) {
                int idx = v * 4 + j;
                x[j] *= s[idx / 49];
            }
            __builtin_nontemporal_store(x, &ov[v]);
        }
    } else if (b < 1024) {
        const float* s = s_g + 2 * NTOK * DM;
        const f32x4* xv = (const f32x4*)x3;
        f32x4* ov = (f32x4*)(out + 1003520);
        const int total4 = 4014080 / 4;
        for (int v = (b - 512) * 256 + t; v < total4; v += 512 * 256) {
            float f = s[v / 49];
            f32x4 x = __builtin_nontemporal_load(&xv[v]);
            x *= f;
            __builtin_nontemporal_store(x, &ov[v]);
        }
    } else if (b < 2048) {
        const float* s = s_g + 1 * NTOK * DM;
        const f32x4* xv = (const f32x4*)x2;
        f32x4* ov = (f32x4*)(out + 5017600);
        const int total4 = 16056320 / 4;
        for (int v = (b - 1024) * 256 + t; v < total4; v += 1024 * 256) {
            float f = s[v / 196];
            f32x4 x = __builtin_nontemporal_load(&xv[v]);
            x *= f;
            __builtin_nontemporal_store(x, &ov[v]);
        }
    } else if (b < 6144) {
        const float* s = s_g;
        const f32x4* xv = (const f32x4*)x1;
        f32x4* ov = (f32x4*)(out + 21073920);
        const int total4 = 64225280 / 4;
        for (int v = (b - 2048) * 256 + t; v < total4; v += 4096 * 256) {
            float f = s[v / 784];
            f32x4 x = __builtin_nontemporal_load(&xv[v]);
            x *= f;
            __builtin_nontemporal_store(x, &ov[v]);
        }
    } else {
        int idx = (b - 6144) * 256 + t;
        out[85299200 + idx] = audio[idx];
    }
}

extern "C" void kernel_launch(void* const* d_in, const int* in_sizes, int n_in,
                              void* d_out, int out_size, void* d_ws, size_t ws_size,
                              hipStream_t stream) {
    const float* x1        = (const float*)d_in[0];
    const float* x2        = (const float*)d_in[1];
    const float* x3        = (const float*)d_in[2];
    const float* x4        = (const float*)d_in[3];
    const float* audio     = (const float*)d_in[4];
    const float* ln_g      = (const float*)d_in[5];
    const float* ln_b      = (const float*)d_in[6];
    const float* in_proj_w = (const float*)d_in[7];
    const float* conv_w    = (const float*)d_in[8];
    const float* conv_b    = (const float*)d_in[9];
    const float* xproj_w   = (const float*)d_in[10];
    const float* dt_w      = (const float*)d_in[11];
    const float* dt_b      = (const float*)d_in[12];
    const float* A_log     = (const float*)d_in[13];
    const float* Dvec      = (const float*)d_in[14];
    const float* out_proj_w= (const float*)d_in[15];
    const float* gate_w    = (const float*)d_in[16];
    const float* gate_b    = (const float*)d_in[17];

    float* ws = (float*)d_ws;

    k_trx<<<24, 256, 0, stream>>>(xproj_w, ws);
    for (int l = 0; l < 3; ++l) {
        const float* src = (l == 0) ? audio : (ws + OFF_A);
        int stride = (l == 0) ? 0 : NTOK * DM;
        K_in<<<256, 256, 0, stream>>>(src, stride, ln_g, ln_b, in_proj_w,
                                      conv_w, conv_b, l, ws);
        K_scan<<<64, 512, 0, stream>>>(dt_w, dt_b, A_log, Dvec, l, ws);
        K_out<<<128, 512, 0, stream>>>(out_proj_w, l, ws);
    }
    K_gates<<<128, 256, 0, stream>>>(gate_w, gate_b, ws);
    k_elem<<<6224, 256, 0, stream>>>(x1, x2, x3, x4, audio, ws + OFF_SG,
                                     (float*)d_out);
}

// Round 10
// 352.936 us; speedup vs baseline: 1.1463x; 1.1463x over previous
//
#include <hip/hip_runtime.h>
#include <hip/hip_bf16.h>
#include <math.h>

// audio (16,5,256) -> 4 branches x 3 mamba layers -> gates scale x1..x4.
// 64 (branch,batch) groups x 8 member-blocks = 512 blocks x 512 threads
// (2 blocks/CU -> 4 waves/SIMD for latency hiding). Member q owns 64-channel
// d_inner slice. Cross-block per layer: dbl partials (240f) + out_proj
// partials (1280f) via agent-scope gbar (2/layer). GEMVs use col-blocking
// (C=2..4 cols/thread) so each LDS activation read feeds 2-4x FMAs; weight
// loads stay lane-coalesced float4 (repacked k-major).

#define NTOK 80
#define DM   256
#define DI   512

typedef float f32x4 __attribute__((ext_vector_type(4)));

__device__ __forceinline__ float silu_f(float v) {
    return v / (1.f + expf(-v));
}
__device__ __forceinline__ float dot4v(f32x4 a, f32x4 b) {
    return a.x*b.x + a.y*b.y + a.z*b.z + a.w*b.w;
}

// ---- workspace layout (float indices) ----
#define OFF_SG    0          // 81920
#define OFF_WINT  81920      // 12 * 262144   [64 k4][1024 c] f4
#define OFF_WOUTT 3227648    // 12 * 131072   [128 k4][256 c] f4
#define OFF_WXT   4800512    // 12 * 24576    [128 k4][48 c]  f4
#define OFF_GWT   5095424    // 4  * 65536    [64 k4][256 c]  f4
#define OFF_DBLP  5357568    // 64 groups * 8 q * 240
#define OFF_OUTP  5480448    // 64 groups * 8 q * 1280
#define OFF_BAR   6135808    // 1024 uints (64 groups * 16)

// ---------------- weight repack: float4-element transpose [R][C4] -> [C4][R] ---
__global__ __launch_bounds__(256) void k_tr(const float* __restrict__ Win,
                                            const float* __restrict__ Wout,
                                            const float* __restrict__ Wx,
                                            const float* __restrict__ gw,
                                            float* __restrict__ ws) {
    if (blockIdx.x == 0) {   // zero group-barrier counters (deterministic)
        unsigned* barp = (unsigned*)(ws + OFF_BAR);
        #pragma unroll
        for (int j = 0; j < 4; ++j) barp[j * 256 + threadIdx.x] = 0u;
    }
    int b = blockIdx.x;
    const float4* src; float4* dst; int R, C4, tile;
    if (b < 768) {                        // Win: 12 x [1024][64]f4
        int mat = b >> 6; tile = b & 63; R = 1024; C4 = 64;
        src = (const float4*)Win + (size_t)mat * 65536;
        dst = (float4*)(ws + OFF_WINT) + (size_t)mat * 65536;
    } else if (b < 1152) {                // Wout: 12 x [256][128]f4
        int bb = b - 768; int mat = bb >> 5; tile = bb & 31; R = 256; C4 = 128;
        src = (const float4*)Wout + (size_t)mat * 32768;
        dst = (float4*)(ws + OFF_WOUTT) + (size_t)mat * 32768;
    } else if (b < 1248) {                // Wx: 12 x [48][128]f4
        int bb = b - 1152; int mat = bb >> 3; tile = bb & 7; R = 48; C4 = 128;
        src = (const float4*)Wx + (size_t)mat * 6144;
        dst = (float4*)(ws + OFF_WXT) + (size_t)mat * 6144;
    } else {                              // gw: 4 x [256][64]f4
        int bb = b - 1248; int mat = bb >> 4; tile = bb & 15; R = 256; C4 = 64;
        src = (const float4*)gw + (size_t)mat * 16384;
        dst = (float4*)(ws + OFF_GWT) + (size_t)mat * 16384;
    }
    int tilesC = C4 >> 5;
    int r0 = (tile / tilesC) << 5, c0 = (tile % tilesC) << 5;
    __shared__ float4 t[32][33];
    int tx = threadIdx.x & 31, ty = threadIdx.x >> 5;
#pragma unroll
    for (int j = 0; j < 4; ++j) {
        int r = ty + j * 8;
        if (r0 + r < R) t[r][tx] = src[(size_t)(r0 + r) * C4 + c0 + tx];
    }
    __syncthreads();
#pragma unroll
    for (int j = 0; j < 4; ++j) {
        int cc = ty + j * 8;
        if (r0 + tx < R) dst[(size_t)(c0 + cc) * R + r0 + tx] = t[tx][cc];
    }
}

// 8-member group barrier; agent scope so correctness is XCD-placement-free.
__device__ __forceinline__ void gbar(unsigned* slot) {
    __syncthreads();
    if (threadIdx.x == 0) {
        __hip_atomic_fetch_add(slot, 1u, __ATOMIC_RELEASE, __HIP_MEMORY_SCOPE_AGENT);
        while (__hip_atomic_load(slot, __ATOMIC_RELAXED, __HIP_MEMORY_SCOPE_AGENT) < 8u)
            __builtin_amdgcn_s_sleep(1);
        (void)__hip_atomic_load(slot, __ATOMIC_ACQUIRE, __HIP_MEMORY_SCOPE_AGENT);
    }
    __syncthreads();
}

// ---------------- split mamba chain + gates: 512 blocks x 512 threads ----------
__global__ __launch_bounds__(512, 4) void k_chain8(
    const float* __restrict__ audio,
    const float* __restrict__ ln_g, const float* __restrict__ ln_b,
    const float* __restrict__ Wc,   const float* __restrict__ bc,
    const float* __restrict__ Wdt,  const float* __restrict__ bdt,
    const float* __restrict__ Alog, const float* __restrict__ Dp,
    const float* __restrict__ gb,   float* __restrict__ ws)
{
    int gid = blockIdx.x & 63;    // group = (branch,batch); all members same XCD
    int q   = blockIdx.x >> 6;    // member 0..7
    int i = gid & 3, b = gid >> 2;
    int tid = threadIdx.x, lane = tid & 63, wave = tid >> 6;
    int dq = q * 64;              // own d_inner slice start

    float* s_g  = ws + OFF_SG;
    float* dblp = ws + OFF_DBLP + (size_t)gid * 8 * 240;
    float* outp = ws + OFF_OUTP + (size_t)gid * 8 * 1280;
    unsigned* bar = (unsigned*)(ws + OFF_BAR) + gid * 16;

    __shared__ __align__(16) float a_l   [1280];   // activations (5x256)
    __shared__ __align__(16) float aln_l [1280];   // LN out (residual base)
    __shared__ __align__(16) float xz_l  [640];    // own: [r][0..63]=xc-pre, [64..127]=z
    __shared__ __align__(16) float xc_l  [320];    // conv+silu out, own 64 ch
    __shared__ __align__(16) float y_l   [320];    // scan out, own 64 ch
    __shared__ __align__(16) float dbl_l [240];
    __shared__ __align__(16) float xp_l  [480];
    __shared__ __align__(16) float part_l[10240];  // K-split partial scratch

    if (tid < 320)
        ((f32x4*)a_l)[tid] = ((const f32x4*)(audio + (size_t)b * 1280))[tid];
    __syncthreads();

    for (int l = 0; l < 3; ++l) {
        int il = i * 3 + l;

        // ---- LayerNorm (redundant per member): wave w<5 handles row w ----
        if (wave < 5) {
            f32x4 x = ((f32x4*)a_l)[wave*64 + lane];
            float s = x.x + x.y + x.z + x.w;
            #pragma unroll
            for (int o = 32; o > 0; o >>= 1) s += __shfl_down(s, o, 64);
            float mu = __shfl(s, 0, 64) * (1.f/256.f);
            f32x4 d = x - mu;
            float v2 = d.x*d.x + d.y*d.y + d.z*d.z + d.w*d.w;
            #pragma unroll
            for (int o = 32; o > 0; o >>= 1) v2 += __shfl_down(v2, o, 64);
            float rstd = rsqrtf(__shfl(v2, 0, 64) * (1.f/256.f) + 1e-5f);
            f32x4 g4 = ((const f32x4*)(ln_g + (size_t)il*DM))[lane];
            f32x4 b4 = ((const f32x4*)(ln_b + (size_t)il*DM))[lane];
            ((f32x4*)aln_l)[wave*64 + lane] = d * rstd * g4 + b4;
        }
        __syncthreads();

        // ---- in_proj: own 128 cols (64 xc-pre + 64 z), C=2, S=8 ----
        {
            int ct = tid & 63, kq = tid >> 6;
            const f32x4* wt = (const f32x4*)(ws + OFF_WINT) + (size_t)il * 65536;
            int cA = dq + ct, cB = 512 + dq + ct;
            const f32x4* a4 = (const f32x4*)aln_l;   // [5][64]
            float accA[5] = {0,0,0,0,0}, accB[5] = {0,0,0,0,0};
            #pragma unroll
            for (int kk = 0; kk < 8; ++kk) {
                int k4 = kq * 8 + kk;
                f32x4 wa = wt[(size_t)k4*1024 + cA];
                f32x4 wb = wt[(size_t)k4*1024 + cB];
                #pragma unroll
                for (int r = 0; r < 5; ++r) {
                    f32x4 av = a4[r*64 + k4];
                    accA[r] += dot4v(wa, av);
                    accB[r] += dot4v(wb, av);
                }
            }
            #pragma unroll
            for (int r = 0; r < 5; ++r) {
                part_l[kq*640 + ct*5 + r]        = accA[r];
                part_l[kq*640 + (ct+64)*5 + r]   = accB[r];
            }
        }
        __syncthreads();
        for (int v = tid; v < 640; v += 512) {
            int c = v / 5, r = v - c*5;
            float s = 0.f;
            #pragma unroll
            for (int kq = 0; kq < 8; ++kq) s += part_l[kq*640 + v];
            xz_l[r*128 + c] = s;
        }
        __syncthreads();

        // ---- depthwise causal conv (k=4) + bias + SiLU on own 64 ch ----
        if (tid < 320) {
            int c = tid & 63, r = tid >> 6;
            int ch = dq + c;
            const float* wr = Wc + ((size_t)il*DI + ch)*4;
            float acc = bc[(size_t)il*DI + ch] + wr[3]*xz_l[r*128 + c];
            if (r >= 1) acc += wr[2]*xz_l[(r-1)*128 + c];
            if (r >= 2) acc += wr[1]*xz_l[(r-2)*128 + c];
            if (r >= 3) acc += wr[0]*xz_l[(r-3)*128 + c];
            xc_l[r*64 + c] = silu_f(acc);
        }
        __syncthreads();

        // ---- x_proj partial over own K=64 (16 k4), S=2 over 480 threads ----
        if (tid < 480) {
            int c = tid % 48, r = (tid / 48) % 5, kh = tid / 240;
            const f32x4* wp = (const f32x4*)(ws + OFF_WXT) + (size_t)il*6144 + c;
            const f32x4* x4 = (const f32x4*)xc_l + r*16 + kh*8;
            float acc = 0.f;
            #pragma unroll
            for (int kk = 0; kk < 8; ++kk)
                acc += dot4v(wp[(size_t)(q*16 + kh*8 + kk)*48], x4[kk]);
            xp_l[tid] = acc;
        }
        __syncthreads();
        if (tid < 240) dblp[q*240 + tid] = xp_l[tid] + xp_l[240 + tid];
        gbar(bar + 2*l);
        if (tid < 240) {
            float s = 0.f;
            #pragma unroll
            for (int q2 = 0; q2 < 8; ++q2) s += dblp[q2*240 + tid];
            dbl_l[tid] = s;
        }
        __syncthreads();

        // ---- scan (dt-proj fused) + D skip + z gate on own 64 ch ----
        if (tid < 64) {
            int d = dq + tid;
            float A[16], h[16];
            const f32x4* al4 = (const f32x4*)(Alog + ((size_t)il*DI + d)*16);
            f32x4 av0 = al4[0], av1 = al4[1], av2 = al4[2], av3 = al4[3];
            A[0]=-expf(av0.x); A[1]=-expf(av0.y); A[2]=-expf(av0.z); A[3]=-expf(av0.w);
            A[4]=-expf(av1.x); A[5]=-expf(av1.y); A[6]=-expf(av1.z); A[7]=-expf(av1.w);
            A[8]=-expf(av2.x); A[9]=-expf(av2.y); A[10]=-expf(av2.z); A[11]=-expf(av2.w);
            A[12]=-expf(av3.x); A[13]=-expf(av3.y); A[14]=-expf(av3.z); A[15]=-expf(av3.w);
            #pragma unroll
            for (int n = 0; n < 16; ++n) h[n] = 0.f;
            const f32x4* wd4 = (const f32x4*)(Wdt + ((size_t)il*DI + d)*16);
            f32x4 w0 = wd4[0], w1 = wd4[1], w2 = wd4[2], w3 = wd4[3];
            float bdtv = bdt[(size_t)il*DI + d];
            float dv   = Dp[(size_t)il*DI + d];
            #pragma unroll
            for (int t = 0; t < 5; ++t) {
                const float* db = dbl_l + t*48;
                float acc = bdtv;
                acc += db[0]*w0.x + db[1]*w0.y + db[2]*w0.z + db[3]*w0.w;
                acc += db[4]*w1.x + db[5]*w1.y + db[6]*w1.z + db[7]*w1.w;
                acc += db[8]*w2.x + db[9]*w2.y + db[10]*w2.z + db[11]*w2.w;
                acc += db[12]*w3.x + db[13]*w3.y + db[14]*w3.z + db[15]*w3.w;
                float dtv = fmaxf(acc, 0.f) + log1pf(expf(-fabsf(acc)));
                float xv  = xc_l[t*64 + tid];
                float zv  = xz_l[t*128 + 64 + tid];
                float dx  = dtv * xv;
                float yacc = 0.f;
                #pragma unroll
                for (int n = 0; n < 16; ++n) {
                    h[n] = expf(dtv*A[n])*h[n] + dx*db[16 + n];
                    yacc += h[n]*db[32 + n];
                }
                y_l[t*64 + tid] = (yacc + xv*dv) * silu_f(zv);
            }
        }
        __syncthreads();

        // ---- out_proj partial: 256 cols, own K=64 (16 k4), C=4, S=8 ----
        {
            int ct = tid & 63, kq = tid >> 6;
            const f32x4* wt = (const f32x4*)(ws + OFF_WOUTT) + (size_t)il * 32768;
            const f32x4* y4 = (const f32x4*)y_l;   // [5][16]
            float acc[4][5];
            #pragma unroll
            for (int cb = 0; cb < 4; ++cb)
                #pragma unroll
                for (int r = 0; r < 5; ++r) acc[cb][r] = 0.f;
            #pragma unroll
            for (int kk = 0; kk < 2; ++kk) {
                int k4l = kq*2 + kk;
                int k4g = q*16 + k4l;
                f32x4 w0 = wt[(size_t)k4g*256 + ct];
                f32x4 w1 = wt[(size_t)k4g*256 + ct + 64];
                f32x4 w2 = wt[(size_t)k4g*256 + ct + 128];
                f32x4 w3 = wt[(size_t)k4g*256 + ct + 192];
                #pragma unroll
                for (int r = 0; r < 5; ++r) {
                    f32x4 yv = y4[r*16 + k4l];
                    acc[0][r] += dot4v(w0, yv);
                    acc[1][r] += dot4v(w1, yv);
                    acc[2][r] += dot4v(w2, yv);
                    acc[3][r] += dot4v(w3, yv);
                }
            }
            #pragma unroll
            for (int cb = 0; cb < 4; ++cb)
                #pragma unroll
                for (int r = 0; r < 5; ++r)
                    part_l[kq*1280 + (cb*64 + ct)*5 + r] = acc[cb][r];
        }
        __syncthreads();
        for (int v = tid; v < 1280; v += 512) {
            int r = v >> 8, c = v & 255;
            float s = 0.f;
            #pragma unroll
            for (int kq = 0; kq < 8; ++kq) s += part_l[kq*1280 + c*5 + r];
            outp[q*1280 + v] = s;
        }
        gbar(bar + 2*l + 1);
        for (int v = tid; v < 1280; v += 512) {
            float s = aln_l[v];
            #pragma unroll
            for (int q2 = 0; q2 < 8; ++q2) s += outp[q2*1280 + v];
            a_l[v] = s;
        }
        __syncthreads();
    }

    // ---- gates: own 32 cols, C=1, S=16; s_g = 1+silu(a@gw^T+gb), permuted ----
    {
        int ct = tid & 31, kq = tid >> 5;
        int gc = q*32 + ct;
        const f32x4* wt = (const f32x4*)(ws + OFF_GWT) + (size_t)i * 16384;
        const f32x4* a4 = (const f32x4*)a_l;   // [5][64]
        float acc[5] = {0,0,0,0,0};
        #pragma unroll
        for (int kk = 0; kk < 4; ++kk) {
            int k4 = kq*4 + kk;
            f32x4 w = wt[(size_t)k4*256 + gc];
            #pragma unroll
            for (int r = 0; r < 5; ++r) acc[r] += dot4v(w, a4[r*64 + k4]);
        }
        #pragma unroll
        for (int r = 0; r < 5; ++r) part_l[kq*160 + ct*5 + r] = acc[r];
    }
    __syncthreads();
    if (tid < 160) {
        int cc = tid / 5, r = tid - cc*5;
        float s = gb[(size_t)i*DM + q*32 + cc];
        #pragma unroll
        for (int kq = 0; kq < 16; ++kq) s += part_l[kq*160 + tid];
        int row = b*5 + r;
        int np  = (i == 0) ? row : (r*16 + b);
        s_g[((size_t)i*NTOK + np)*DM + q*32 + cc] = 1.f + silu_f(s);
    }
}

// ---------------- fused elementwise: o = x * s[plane], nontemporal ----------
__global__ __launch_bounds__(256) void k_elem(
    const float* __restrict__ x1, const float* __restrict__ x2,
    const float* __restrict__ x3, const float* __restrict__ x4,
    const float* __restrict__ audio, const float* __restrict__ s_g,
    float* __restrict__ out) {
    int b = blockIdx.x;
    int t = threadIdx.x;

    if (b < 512) {
        const float* s = s_g + 3 * NTOK * DM;
        const f32x4* xv = (const f32x4*)x4;
        f32x4* ov = (f32x4*)out;
        const int total4 = 1003520 / 4;
        for (int v = b * 256 + t; v < total4; v += 512 * 256) {
            f32x4 x = __builtin_nontemporal_load(&xv[v]);
#pragma unroll
            for (int j = 0; j < 4; ++j) {
                int idx = v * 4 + j;
                x[j] *= s[idx / 49];
            }
            __builtin_nontemporal_store(x, &ov[v]);
        }
    } else if (b < 1024) {
        const float* s = s_g + 2 * NTOK * DM;
        const f32x4* xv = (const f32x4*)x3;
        f32x4* ov = (f32x4*)(out + 1003520);
        const int total4 = 4014080 / 4;
        for (int v = (b - 512) * 256 + t; v < total4; v += 512 * 256) {
            float f = s[v / 49];
            f32x4 x = __builtin_nontemporal_load(&xv[v]);
            x *= f;
            __builtin_nontemporal_store(x, &ov[v]);
        }
    } else if (b < 2048) {
        const float* s = s_g + 1 * NTOK * DM;
        const f32x4* xv = (const f32x4*)x2;
        f32x4* ov = (f32x4*)(out + 5017600);
        const int total4 = 16056320 / 4;
        for (int v = (b - 1024) * 256 + t; v < total4; v += 1024 * 256) {
            float f = s[v / 196];
            f32x4 x = __builtin_nontemporal_load(&xv[v]);
            x *= f;
            __builtin_nontemporal_store(x, &ov[v]);
        }
    } else if (b < 6144) {
        const float* s = s_g;
        const f32x4* xv = (const f32x4*)x1;
        f32x4* ov = (f32x4*)(out + 21073920);
        const int total4 = 64225280 / 4;
        for (int v = (b - 2048) * 256 + t; v < total4; v += 4096 * 256) {
            float f = s[v / 784];
            f32x4 x = __builtin_nontemporal_load(&xv[v]);
            x *= f;
            __builtin_nontemporal_store(x, &ov[v]);
        }
    } else {
        int idx = (b - 6144) * 256 + t;
        out[85299200 + idx] = audio[idx];
    }
}

extern "C" void kernel_launch(void* const* d_in, const int* in_sizes, int n_in,
                              void* d_out, int out_size, void* d_ws, size_t ws_size,
                              hipStream_t stream) {
    const float* x1        = (const float*)d_in[0];
    const float* x2        = (const float*)d_in[1];
    const float* x3        = (const float*)d_in[2];
    const float* x4        = (const float*)d_in[3];
    const float* audio     = (const float*)d_in[4];
    const float* ln_g      = (const float*)d_in[5];
    const float* ln_b      = (const float*)d_in[6];
    const float* in_proj_w = (const float*)d_in[7];
    const float* conv_w    = (const float*)d_in[8];
    const float* conv_b    = (const float*)d_in[9];
    const float* xproj_w   = (const float*)d_in[10];
    const float* dt_w      = (const float*)d_in[11];
    const float* dt_b      = (const float*)d_in[12];
    const float* A_log     = (const float*)d_in[13];
    const float* Dvec      = (const float*)d_in[14];
    const float* out_proj_w= (const float*)d_in[15];
    const float* gate_w    = (const float*)d_in[16];
    const float* gate_b    = (const float*)d_in[17];

    float* ws = (float*)d_ws;

    k_tr<<<1312, 256, 0, stream>>>(in_proj_w, out_proj_w, xproj_w, gate_w, ws);
    k_chain8<<<512, 512, 0, stream>>>(audio, ln_g, ln_b, conv_w, conv_b,
                                      dt_w, dt_b, A_log, Dvec, gate_b, ws);
    k_elem<<<6224, 256, 0, stream>>>(x1, x2, x3, x4, audio, ws + OFF_SG,
                                     (float*)d_out);
}

// Round 11
// 238.927 us; speedup vs baseline: 1.6933x; 1.4772x over previous
//
#include <hip/hip_runtime.h>
#include <hip/hip_bf16.h>
#include <math.h>

// audio (16,5,256) -> 4 branches x 3 mamba layers -> gates scale x1..x4.
// R6 structure (best: 64 groups x 4 members, 256 blocks x 512 thr, 2 gbars/
// layer) + bf16 k8-packed weights (halves the measured 182MB weight re-stream)
// + C=2 col-pairs per thread (halves LDS act reads per FMA -> VALU-bound).

#define NTOK 80
#define DM   256
#define DI   512

typedef float f32x4 __attribute__((ext_vector_type(4)));

__device__ __forceinline__ float silu_f(float v) {
    return v / (1.f + expf(-v));
}
__device__ __forceinline__ float dot4v(f32x4 a, f32x4 b) {
    return a.x*b.x + a.y*b.y + a.z*b.z + a.w*b.w;
}
__device__ __forceinline__ unsigned pack2bf(float lo, float hi) {
    unsigned ul = __float_as_uint(lo), uh = __float_as_uint(hi);
    unsigned bl = (ul + 0x7FFFu + ((ul >> 16) & 1u)) >> 16;
    unsigned bh = (uh + 0x7FFFu + ((uh >> 16) & 1u)) >> 16;
    return bl | (bh << 16);
}
__device__ __forceinline__ f32x4 unpk4(unsigned x, unsigned y) {
    f32x4 r;
    r.x = __uint_as_float(x << 16); r.y = __uint_as_float(x & 0xFFFF0000u);
    r.z = __uint_as_float(y << 16); r.w = __uint_as_float(y & 0xFFFF0000u);
    return r;
}

// ---- workspace layout (float indices) ----
#define OFF_SG    0          // 81920
#define OFF_WIN8  81920      // 12 il * [32 k8][1024 c] uint4 = 1572864 floats
#define OFF_WOUT8 1654784    // 12 il * [64 k8][256 c] uint4 = 786432
#define OFF_GW8   2441216    // 4 i  * [32 k8][256 c] uint4 = 131072
#define OFF_WXT   2572288    // 12 * [128 k4][48 c] f4 (fp32) = 294912
#define OFF_DBLP  2867200    // 64 groups * 4 q * 240
#define OFF_OUTP  2928640    // 64 groups * 4 q * 1280
#define OFF_BAR   3256320    // 1024 uints

// ---------------- weight repack/convert: 704 blocks x 256 ----------------
// Win/Wout/gw -> bf16 [k8][c] uint4 tiles; Wx -> fp32 [k4][48] (as R6).
__global__ __launch_bounds__(256) void k_tr(const float* __restrict__ Win,
                                            const float* __restrict__ Wout,
                                            const float* __restrict__ Wx,
                                            const float* __restrict__ gw,
                                            float* __restrict__ ws) {
    __shared__ __align__(16) float SH[8256];   // 64*129 floats
    int b = blockIdx.x, tid = threadIdx.x;
    if (b == 0) {
        unsigned* barp = (unsigned*)(ws + OFF_BAR);
        #pragma unroll
        for (int j = 0; j < 4; ++j) barp[j * 256 + tid] = 0u;
    }

    if (b < 608) {
        const float* src; unsigned* dst; int rowStride, Ctot, c0, k0;
        if (b < 384) {               // Win: 12 il x 16 cb x 2 kh
            int il = b / 32, rest = b % 32, cb = rest >> 1, kh = rest & 1;
            src = Win + (size_t)il * 1024 * 256; rowStride = 256; Ctot = 1024;
            c0 = cb * 64; k0 = kh * 128;
            dst = (unsigned*)(ws + OFF_WIN8) + (size_t)il * 32768 * 4;
        } else if (b < 576) {        // Wout: 12 il x 4 cb x 4 kq
            int t = b - 384; int il = t / 16, rest = t % 16, cb = rest >> 2, kq = rest & 3;
            src = Wout + (size_t)il * 256 * 512; rowStride = 512; Ctot = 256;
            c0 = cb * 64; k0 = kq * 128;
            dst = (unsigned*)(ws + OFF_WOUT8) + (size_t)il * 16384 * 4;
        } else {                     // gw: 4 i x 4 cb x 2 kh
            int t = b - 576; int i = t / 8, rest = t % 8, cb = rest >> 1, kh = rest & 1;
            src = gw + (size_t)i * 256 * 256; rowStride = 256; Ctot = 256;
            c0 = cb * 64; k0 = kh * 128;
            dst = (unsigned*)(ws + OFF_GW8) + (size_t)i * 8192 * 4;
        }
        // read 64 rows x 128 floats, coalesced
        for (int idx = tid; idx < 64 * 32; idx += 256) {
            int row = idx >> 5, kq4 = idx & 31;
            const float4 v = *(const float4*)(src + (size_t)(c0 + row) * rowStride
                                              + k0 + kq4 * 4);
            float* f = SH + row * 129 + kq4 * 4;
            f[0] = v.x; f[1] = v.y; f[2] = v.z; f[3] = v.w;
        }
        __syncthreads();
        // convert + write: 16 k8 x 64 c
        uint4* d4 = (uint4*)dst;
        for (int idx = tid; idx < 1024; idx += 256) {
            int k8l = idx >> 6, c = idx & 63;
            const float* f = SH + c * 129 + k8l * 8;
            uint4 o;
            o.x = pack2bf(f[0], f[1]); o.y = pack2bf(f[2], f[3]);
            o.z = pack2bf(f[4], f[5]); o.w = pack2bf(f[6], f[7]);
            d4[((size_t)(k0 / 8 + k8l)) * Ctot + c0 + c] = o;
        }
    } else {                         // Wx fp32 repack: 96 blocks, 32x32 f4 tiles
        int bb = b - 608; int mat = bb >> 3, tile = bb & 7;
        const float4* src = (const float4*)Wx + (size_t)mat * 6144;
        float4* dst = (float4*)(ws + OFF_WXT) + (size_t)mat * 6144;
        int R = 48, C4 = 128, tilesC = 4;
        int r0 = (tile / tilesC) << 5, cc0 = (tile % tilesC) << 5;
        float4* t4 = (float4*)SH;    // [32][33]
        int tx = tid & 31, ty = tid >> 5;
        #pragma unroll
        for (int j = 0; j < 4; ++j) {
            int r = ty + j * 8;
            if (r0 + r < R) t4[r * 33 + tx] = src[(size_t)(r0 + r) * C4 + cc0 + tx];
        }
        __syncthreads();
        #pragma unroll
        for (int j = 0; j < 4; ++j) {
            int cc = ty + j * 8;
            if (r0 + tx < R) dst[(size_t)(cc0 + cc) * R + r0 + tx] = t4[tx * 33 + cc];
        }
    }
}

// 4-member group barrier; agent scope so correctness is XCD-placement-free.
__device__ __forceinline__ void gbar(unsigned* slot) {
    __syncthreads();
    if (threadIdx.x == 0) {
        __hip_atomic_fetch_add(slot, 1u, __ATOMIC_RELEASE, __HIP_MEMORY_SCOPE_AGENT);
        while (__hip_atomic_load(slot, __ATOMIC_RELAXED, __HIP_MEMORY_SCOPE_AGENT) < 4u)
            __builtin_amdgcn_s_sleep(1);
        (void)__hip_atomic_load(slot, __ATOMIC_ACQUIRE, __HIP_MEMORY_SCOPE_AGENT);
    }
    __syncthreads();
}

// ---------------- split mamba chain + gates: 256 blocks x 512 threads ----------
__global__ __launch_bounds__(512) void k_chain4b(
    const float* __restrict__ audio,
    const float* __restrict__ ln_g, const float* __restrict__ ln_b,
    const float* __restrict__ Wc,   const float* __restrict__ bc,
    const float* __restrict__ Wdt,  const float* __restrict__ bdt,
    const float* __restrict__ Alog, const float* __restrict__ Dp,
    const float* __restrict__ gb,   float* __restrict__ ws)
{
    int gid = blockIdx.x & 63;    // group = (branch,batch); members co-XCD
    int q   = blockIdx.x >> 6;    // member 0..3
    int i = gid & 3, b = gid >> 2;
    int tid = threadIdx.x, lane = tid & 63, wave = tid >> 6;
    int dq = q * 128;

    float* s_g  = ws + OFF_SG;
    float* dblp = ws + OFF_DBLP + (size_t)gid * 4 * 240;
    float* outp = ws + OFF_OUTP + (size_t)gid * 4 * 1280;
    unsigned* bar = (unsigned*)(ws + OFF_BAR) + gid * 16;

    __shared__ __align__(16) float a_l   [1280];
    __shared__ __align__(16) float aln_l [1280];
    __shared__ __align__(16) float xz_l  [1280];  // [r][0..127]=xc-pre, [128..255]=z
    __shared__ __align__(16) float xc_l  [640];
    __shared__ __align__(16) float y_l   [640];
    __shared__ __align__(16) float dbl_l [240];
    __shared__ __align__(16) float xp_l  [480];
    __shared__ __align__(16) float part_l[5120];  // K-split partials

    if (tid < 320)
        ((f32x4*)a_l)[tid] = ((const f32x4*)(audio + (size_t)b * 1280))[tid];
    __syncthreads();

    for (int l = 0; l < 3; ++l) {
        int il = i * 3 + l;

        // ---- LayerNorm (redundant per member) ----
        if (wave < 5) {
            f32x4 x = ((f32x4*)a_l)[wave*64 + lane];
            float s = x.x + x.y + x.z + x.w;
            #pragma unroll
            for (int o = 32; o > 0; o >>= 1) s += __shfl_down(s, o, 64);
            float mu = __shfl(s, 0, 64) * (1.f/256.f);
            f32x4 d = x - mu;
            float v2 = d.x*d.x + d.y*d.y + d.z*d.z + d.w*d.w;
            #pragma unroll
            for (int o = 32; o > 0; o >>= 1) v2 += __shfl_down(v2, o, 64);
            float rstd = rsqrtf(__shfl(v2, 0, 64) * (1.f/256.f) + 1e-5f);
            f32x4 g4 = ((const f32x4*)(ln_g + (size_t)il*DM))[lane];
            f32x4 b4 = ((const f32x4*)(ln_b + (size_t)il*DM))[lane];
            ((f32x4*)aln_l)[wave*64 + lane] = d * rstd * g4 + b4;
        }
        __syncthreads();

        // ---- in_proj: own 256 cols as 128 pairs, C=2, K split 4 (kq) ----
        {
            int cp = tid & 127, kq = tid >> 7;
            int lc, cA;
            if (cp < 64) { lc = 2*cp;       cA = dq + 2*cp; }
            else         { lc = 2*cp;       cA = 512 + dq + 2*(cp-64); }
            const uint4* W8 = (const uint4*)(ws + OFF_WIN8) + (size_t)il * 32768;
            const f32x4* a4 = (const f32x4*)aln_l;   // [5][64]
            float accA[5] = {0,0,0,0,0}, accB[5] = {0,0,0,0,0};
            #pragma unroll
            for (int j = 0; j < 8; ++j) {
                int k8 = kq*8 + j;
                uint4 wa = W8[(size_t)k8*1024 + cA];
                uint4 wb = W8[(size_t)k8*1024 + cA + 1];
                f32x4 wa0 = unpk4(wa.x, wa.y), wa1 = unpk4(wa.z, wa.w);
                f32x4 wb0 = unpk4(wb.x, wb.y), wb1 = unpk4(wb.z, wb.w);
                #pragma unroll
                for (int r = 0; r < 5; ++r) {
                    f32x4 a0 = a4[r*64 + k8*2], a1 = a4[r*64 + k8*2 + 1];
                    accA[r] += dot4v(wa0, a0) + dot4v(wa1, a1);
                    accB[r] += dot4v(wb0, a0) + dot4v(wb1, a1);
                }
            }
            #pragma unroll
            for (int r = 0; r < 5; ++r) {
                part_l[kq*1280 + r*256 + lc]     = accA[r];
                part_l[kq*1280 + r*256 + lc + 1] = accB[r];
            }
        }
        __syncthreads();
        for (int v = tid; v < 1280; v += 512)
            xz_l[v] = part_l[v] + part_l[1280+v] + part_l[2560+v] + part_l[3840+v];
        __syncthreads();

        // ---- depthwise causal conv (k=4) + bias + SiLU on own 128 ch ----
        for (int v = tid; v < 640; v += 512) {
            int r = v >> 7, dl = v & 127;
            int ch = dq + dl;
            const float* wr = Wc + ((size_t)il*DI + ch)*4;
            float acc = bc[(size_t)il*DI + ch] + wr[3]*xz_l[r*256 + dl];
            if (r >= 1) acc += wr[2]*xz_l[(r-1)*256 + dl];
            if (r >= 2) acc += wr[1]*xz_l[(r-2)*256 + dl];
            if (r >= 3) acc += wr[0]*xz_l[(r-3)*256 + dl];
            xc_l[r*128 + dl] = silu_f(acc);
        }
        __syncthreads();

        // ---- x_proj partial over own K=128 (fp32, as R6) ----
        if (tid < 480) {
            int c = tid % 48, r = (tid / 48) % 5, kh = tid / 240;
            const f32x4* wp = (const f32x4*)(ws + OFF_WXT) + (size_t)il*6144 + c;
            const f32x4* x4 = (const f32x4*)xc_l + r*32 + kh*16;
            float acc = 0.f;
            #pragma unroll
            for (int kk = 0; kk < 16; ++kk)
                acc += dot4v(wp[(size_t)(q*32 + kh*16 + kk)*48], x4[kk]);
            xp_l[tid] = acc;
        }
        __syncthreads();
        if (tid < 240) dblp[q*240 + tid] = xp_l[tid] + xp_l[240 + tid];
        gbar(bar + 2*l);
        if (tid < 240)
            dbl_l[tid] = dblp[tid] + dblp[240+tid] + dblp[480+tid] + dblp[720+tid];
        __syncthreads();

        // ---- scan (dt-proj fused) + D skip + z gate on own 128 ch ----
        if (tid < 128) {
            int d = dq + tid;
            float A[16], h[16];
            const f32x4* al4 = (const f32x4*)(Alog + ((size_t)il*DI + d)*16);
            f32x4 av0 = al4[0], av1 = al4[1], av2 = al4[2], av3 = al4[3];
            A[0]=-expf(av0.x); A[1]=-expf(av0.y); A[2]=-expf(av0.z); A[3]=-expf(av0.w);
            A[4]=-expf(av1.x); A[5]=-expf(av1.y); A[6]=-expf(av1.z); A[7]=-expf(av1.w);
            A[8]=-expf(av2.x); A[9]=-expf(av2.y); A[10]=-expf(av2.z); A[11]=-expf(av2.w);
            A[12]=-expf(av3.x); A[13]=-expf(av3.y); A[14]=-expf(av3.z); A[15]=-expf(av3.w);
            #pragma unroll
            for (int n = 0; n < 16; ++n) h[n] = 0.f;
            const f32x4* wd4 = (const f32x4*)(Wdt + ((size_t)il*DI + d)*16);
            f32x4 w0 = wd4[0], w1 = wd4[1], w2 = wd4[2], w3 = wd4[3];
            float bdtv = bdt[(size_t)il*DI + d];
            float dv   = Dp[(size_t)il*DI + d];
            #pragma unroll
            for (int t = 0; t < 5; ++t) {
                const float* db = dbl_l + t*48;
                float acc = bdtv;
                acc += db[0]*w0.x + db[1]*w0.y + db[2]*w0.z + db[3]*w0.w;
                acc += db[4]*w1.x + db[5]*w1.y + db[6]*w1.z + db[7]*w1.w;
                acc += db[8]*w2.x + db[9]*w2.y + db[10]*w2.z + db[11]*w2.w;
                acc += db[12]*w3.x + db[13]*w3.y + db[14]*w3.z + db[15]*w3.w;
                float dtv = fmaxf(acc, 0.f) + log1pf(expf(-fabsf(acc)));
                float xv  = xc_l[t*128 + tid];
                float zv  = xz_l[t*256 + 128 + tid];
                float dx  = dtv * xv;
                float yacc = 0.f;
                #pragma unroll
                for (int n = 0; n < 16; ++n) {
                    h[n] = expf(dtv*A[n])*h[n] + dx*db[16 + n];
                    yacc += h[n]*db[32 + n];
                }
                y_l[t*128 + tid] = (yacc + xv*dv) * silu_f(zv);
            }
        }
        __syncthreads();

        // ---- out_proj partial: 256 cols as 128 pairs, own K=128, split 4 ----
        {
            int cp = tid & 127, kq = tid >> 7;
            int cA = 2*cp;
            const uint4* W8 = (const uint4*)(ws + OFF_WOUT8) + (size_t)il * 16384;
            const f32x4* y4 = (const f32x4*)y_l;   // [5][32]
            float accA[5] = {0,0,0,0,0}, accB[5] = {0,0,0,0,0};
            #pragma unroll
            for (int j = 0; j < 4; ++j) {
                int k8l = kq*4 + j;
                int k8g = q*16 + k8l;
                uint4 wa = W8[(size_t)k8g*256 + cA];
                uint4 wb = W8[(size_t)k8g*256 + cA + 1];
                f32x4 wa0 = unpk4(wa.x, wa.y), wa1 = unpk4(wa.z, wa.w);
                f32x4 wb0 = unpk4(wb.x, wb.y), wb1 = unpk4(wb.z, wb.w);
                #pragma unroll
                for (int r = 0; r < 5; ++r) {
                    f32x4 y0 = y4[r*32 + k8l*2], y1 = y4[r*32 + k8l*2 + 1];
                    accA[r] += dot4v(wa0, y0) + dot4v(wa1, y1);
                    accB[r] += dot4v(wb0, y0) + dot4v(wb1, y1);
                }
            }
            #pragma unroll
            for (int r = 0; r < 5; ++r) {
                part_l[kq*1280 + r*256 + cA]     = accA[r];
                part_l[kq*1280 + r*256 + cA + 1] = accB[r];
            }
        }
        __syncthreads();
        for (int v = tid; v < 1280; v += 512)
            outp[q*1280 + v] = part_l[v] + part_l[1280+v] + part_l[2560+v] + part_l[3840+v];
        gbar(bar + 2*l + 1);
        for (int v = tid; v < 1280; v += 512)
            a_l[v] = aln_l[v] + outp[v] + outp[1280+v] + outp[2560+v] + outp[3840+v];
        __syncthreads();
    }

    // ---- gates: own 64 cols as 32 pairs, K=256 split 16 (kq) ----
    {
        int cp = tid & 31, kq = tid >> 5;
        int gA = q*64 + 2*cp;
        const uint4* G8 = (const uint4*)(ws + OFF_GW8) + (size_t)i * 8192;
        const f32x4* a4 = (const f32x4*)a_l;   // [5][64]
        float accA[5] = {0,0,0,0,0}, accB[5] = {0,0,0,0,0};
        #pragma unroll
        for (int j = 0; j < 2; ++j) {
            int k8 = kq*2 + j;
            uint4 wa = G8[(size_t)k8*256 + gA];
            uint4 wb = G8[(size_t)k8*256 + gA + 1];
            f32x4 wa0 = unpk4(wa.x, wa.y), wa1 = unpk4(wa.z, wa.w);
            f32x4 wb0 = unpk4(wb.x, wb.y), wb1 = unpk4(wb.z, wb.w);
            #pragma unroll
            for (int r = 0; r < 5; ++r) {
                f32x4 a0 = a4[r*64 + k8*2], a1 = a4[r*64 + k8*2 + 1];
                accA[r] += dot4v(wa0, a0) + dot4v(wa1, a1);
                accB[r] += dot4v(wb0, a0) + dot4v(wb1, a1);
            }
        }
        #pragma unroll
        for (int r = 0; r < 5; ++r) {
            part_l[kq*320 + r*64 + 2*cp]     = accA[r];
            part_l[kq*320 + r*64 + 2*cp + 1] = accB[r];
        }
    }
    __syncthreads();
    if (tid < 320) {
        int r = tid >> 6, lc = tid & 63;
        float s = gb[(size_t)i*DM + q*64 + lc];
        #pragma unroll
        for (int kq = 0; kq < 16; ++kq) s += part_l[kq*320 + tid];
        int row = b*5 + r;
        int np  = (i == 0) ? row : (r*16 + b);
        s_g[((size_t)i*NTOK + np)*DM + q*64 + lc] = 1.f + silu_f(s);
    }
}

// ---------------- fused elementwise: o = x * s[plane], nontemporal ----------
__global__ __launch_bounds__(256) void k_elem(
    const float* __restrict__ x1, const float* __restrict__ x2,
    const float* __restrict__ x3, const float* __restrict__ x4,
    const float* __restrict__ audio, const float* __restrict__ s_g,
    float* __restrict__ out) {
    int b = blockIdx.x;
    int t = threadIdx.x;

    if (b < 512) {
        const float* s = s_g + 3 * NTOK * DM;
        const f32x4* xv = (const f32x4*)x4;
        f32x4* ov = (f32x4*)out;
        const int total4 = 1003520 / 4;
        for (int v = b * 256 + t; v < total4; v += 512 * 256) {
            f32x4 x = __builtin_nontemporal_load(&xv[v]);
#pragma unroll
            for (int j = 0; j < 4; ++j) {
                int idx = v * 4 + j;
                x[j] *= s[idx / 49];
            }
            __builtin_nontemporal_store(x, &ov[v]);
        }
    } else if (b < 1024) {
        const float* s = s_g + 2 * NTOK * DM;
        const f32x4* xv = (const f32x4*)x3;
        f32x4* ov = (f32x4*)(out + 1003520);
        const int total4 = 4014080 / 4;
        for (int v = (b - 512) * 256 + t; v < total4; v += 512 * 256) {
            float f = s[v / 49];
            f32x4 x = __builtin_nontemporal_load(&xv[v]);
            x *= f;
            __builtin_nontemporal_store(x, &ov[v]);
        }
    } else if (b < 2048) {
        const float* s = s_g + 1 * NTOK * DM;
        const f32x4* xv = (const f32x4*)x2;
        f32x4* ov = (f32x4*)(out + 5017600);
        const int total4 = 16056320 / 4;
        for (int v = (b - 1024) * 256 + t; v < total4; v += 1024 * 256) {
            float f = s[v / 196];
            f32x4 x = __builtin_nontemporal_load(&xv[v]);
            x *= f;
            __builtin_nontemporal_store(x, &ov[v]);
        }
    } else if (b < 6144) {
        const float* s = s_g;
        const f32x4* xv = (const f32x4*)x1;
        f32x4* ov = (f32x4*)(out + 21073920);
        const int total4 = 64225280 / 4;
        for (int v = (b - 2048) * 256 + t; v < total4; v += 4096 * 256) {
            float f = s[v / 784];
            f32x4 x = __builtin_nontemporal_load(&xv[v]);
            x *= f;
            __builtin_nontemporal_store(x, &ov[v]);
        }
    } else {
        int idx = (b - 6144) * 256 + t;
        out[85299200 + idx] = audio[idx];
    }
}

extern "C" void kernel_launch(void* const* d_in, const int* in_sizes, int n_in,
                              void* d_out, int out_size, void* d_ws, size_t ws_size,
                              hipStream_t stream) {
    const float* x1        = (const float*)d_in[0];
    const float* x2        = (const float*)d_in[1];
    const float* x3        = (const float*)d_in[2];
    const float* x4        = (const float*)d_in[3];
    const float* audio     = (const float*)d_in[4];
    const float* ln_g      = (const float*)d_in[5];
    const float* ln_b      = (const float*)d_in[6];
    const float* in_proj_w = (const float*)d_in[7];
    const float* conv_w    = (const float*)d_in[8];
    const float* conv_b    = (const float*)d_in[9];
    const float* xproj_w   = (const float*)d_in[10];
    const float* dt_w      = (const float*)d_in[11];
    const float* dt_b      = (const float*)d_in[12];
    const float* A_log     = (const float*)d_in[13];
    const float* Dvec      = (const float*)d_in[14];
    const float* out_proj_w= (const float*)d_in[15];
    const float* gate_w    = (const float*)d_in[16];
    const float* gate_b    = (const float*)d_in[17];

    float* ws = (float*)d_ws;

    k_tr<<<704, 256, 0, stream>>>(in_proj_w, out_proj_w, xproj_w, gate_w, ws);
    k_chain4b<<<256, 512, 0, stream>>>(audio, ln_g, ln_b, conv_w, conv_b,
                                       dt_w, dt_b, A_log, Dvec, gate_b, ws);
    k_elem<<<6224, 256, 0, stream>>>(x1, x2, x3, x4, audio, ws + OFF_SG,
                                     (float*)d_out);
}